// Round 12
// baseline (1099.399 us; speedup 1.0000x reference)
//
#include <hip/hip_runtime.h>
#include <math.h>

#define N_NODES 4096
#define EDGES   131072
#define INDIM   10
#define H       128
#define LAYERS  4
#define NHEADS  4
#define HDIM    32
#define FFDIM   512
#define KCH     16         // key chunks for flash-attention partials
#define ATTN_SCALE 0.17677669529663687f  // 1/sqrt(32)
#define DEFER_THR 8.0f     // lazy-max threshold: rescale only when sv > m + THR

typedef _Float16 half2_t __attribute__((ext_vector_type(2)));

// v_dot2_f32_f16: d = a.x*b.x + a.y*b.y + c  (2 MACs/instr, fp32 accumulate)
__device__ __forceinline__ float fdot2(unsigned int a, unsigned int b, float c) {
#if __has_builtin(__builtin_amdgcn_fdot2)
    return __builtin_amdgcn_fdot2(__builtin_bit_cast(half2_t, a),
                                  __builtin_bit_cast(half2_t, b), c, false);
#else
    float r;
    asm("v_dot2_f32_f16 %0, %1, %2, %3" : "=v"(r) : "v"(a), "v"(b), "v"(c));
    return r;
#endif
}

// v_cvt_pkrtz_f16_f32: pack two floats to half2 (round-toward-zero).
// NOTE: the builtin returns __fp16 ext_vector_type(2), which clang treats as
// a DIFFERENT type from _Float16 vectors — use auto + bit_cast (round-10 fix).
__device__ __forceinline__ unsigned int pack2(float a, float b) {
    auto h = __builtin_amdgcn_cvt_pkrtz(a, b);   // a -> low, b -> high
    return __builtin_bit_cast(unsigned int, h);
}

// ---------------------------------------------------------------------------
// input projection: h[n][j] = b_in[j] + sum_k x[n][k] * W_in[k][j]   (K=10)
// ---------------------------------------------------------------------------
__global__ __launch_bounds__(128) void in_proj_kernel(
    const float* __restrict__ x, const float* __restrict__ W_in,
    const float* __restrict__ b_in, float* __restrict__ h)
{
    int n = blockIdx.x;
    int j = threadIdx.x;
    float acc = b_in[j];
    #pragma unroll
    for (int k = 0; k < INDIM; ++k)
        acc += x[n * INDIM + k] * W_in[k * H + j];
    h[n * H + j] = acc;
}

// ---------------------------------------------------------------------------
// layernorm over last dim (128). one wave per row, 2 elements per lane.
// ---------------------------------------------------------------------------
__global__ __launch_bounds__(64) void layernorm_kernel(
    const float* __restrict__ h, const float* __restrict__ g,
    const float* __restrict__ b, float* __restrict__ out)
{
    int n = blockIdx.x;
    int t = threadIdx.x;
    float a0 = h[n * H + t];
    float a1 = h[n * H + t + 64];
    float sum = a0 + a1;
    float sq  = a0 * a0 + a1 * a1;
    #pragma unroll
    for (int off = 1; off < 64; off <<= 1) {
        sum += __shfl_xor(sum, off, 64);
        sq  += __shfl_xor(sq,  off, 64);
    }
    float mu  = sum * (1.0f / H);
    float var = sq * (1.0f / H) - mu * mu;
    float r   = rsqrtf(var + 1e-5f);
    out[n * H + t]      = (a0 - mu) * r * g[t]      + b[t];
    out[n * H + t + 64] = (a1 - mu) * r * g[t + 64] + b[t + 64];
}

// ---------------------------------------------------------------------------
// shared tiled-GEMM body: C[r][c] = (RES ? resid : 0) + act(bias[c] + A@W)
// A [rows,K] rm, W [K,M] rm.  BM=64, BN=64, BK=32, 256 thr, 4x4 micro.
// ---------------------------------------------------------------------------
template<bool RELU, bool RES>
__device__ __forceinline__ void gemm_body(
    const float* __restrict__ A, const float* __restrict__ W,
    const float* __restrict__ bias, const float* __restrict__ resid,
    float* __restrict__ C, int K, int M, int colbase, int rowbase,
    float (*As)[68], float (*Ws)[68])
{
    int tid = threadIdx.x;
    int cx = tid % 16;           // col group: cols cx*4..+3
    int ry = tid / 16;           // row group: rows ry*4..+3

    int lr = tid % 64;           // A-load row
    int kq = tid / 64;           // A-load k-subblock (0..3)
    int wk  = tid / 8;           // W-load k row (0..31)
    int wc0 = (tid % 8) * 8;     // W-load col start

    float acc[4][4];
    #pragma unroll
    for (int i = 0; i < 4; ++i)
        #pragma unroll
        for (int j = 0; j < 4; ++j) acc[i][j] = 0.f;

    for (int kb = 0; kb < K; kb += 32) {
        #pragma unroll
        for (int h2 = 0; h2 < 2; ++h2) {
            int k0 = kq * 8 + h2 * 4;
            float4 a4 = *(const float4*)&A[(size_t)(rowbase + lr) * K + kb + k0];
            As[k0 + 0][lr] = a4.x;
            As[k0 + 1][lr] = a4.y;
            As[k0 + 2][lr] = a4.z;
            As[k0 + 3][lr] = a4.w;
        }
        *(float4*)&Ws[wk][wc0]     = *(const float4*)&W[(size_t)(kb + wk) * M + colbase + wc0];
        *(float4*)&Ws[wk][wc0 + 4] = *(const float4*)&W[(size_t)(kb + wk) * M + colbase + wc0 + 4];
        __syncthreads();

        #pragma unroll
        for (int kk = 0; kk < 32; ++kk) {
            float4 a = *(const float4*)&As[kk][ry * 4];
            float4 w = *(const float4*)&Ws[kk][cx * 4];
            float av[4] = {a.x, a.y, a.z, a.w};
            float wv[4] = {w.x, w.y, w.z, w.w};
            #pragma unroll
            for (int i = 0; i < 4; ++i)
                #pragma unroll
                for (int j = 0; j < 4; ++j)
                    acc[i][j] += av[i] * wv[j];
        }
        __syncthreads();
    }

    #pragma unroll
    for (int i = 0; i < 4; ++i) {
        int r  = rowbase + ry * 4 + i;
        int c0 = colbase + cx * 4;
        float v0 = acc[i][0] + bias[c0 + 0];
        float v1 = acc[i][1] + bias[c0 + 1];
        float v2 = acc[i][2] + bias[c0 + 2];
        float v3 = acc[i][3] + bias[c0 + 3];
        if (RELU) {
            v0 = fmaxf(v0, 0.f); v1 = fmaxf(v1, 0.f);
            v2 = fmaxf(v2, 0.f); v3 = fmaxf(v3, 0.f);
        }
        if (RES) {
            const float4 rr = *(const float4*)&resid[(size_t)r * M + c0];
            v0 += rr.x; v1 += rr.y; v2 += rr.z; v3 += rr.w;
        }
        float4 outv = make_float4(v0, v1, v2, v3);
        *(float4*)&C[(size_t)r * M + c0] = outv;
    }
}

template<bool RELU, bool RES>
__global__ __launch_bounds__(256) void gemm_kernel(
    const float* __restrict__ A, const float* __restrict__ W,
    const float* __restrict__ bias, const float* __restrict__ resid,
    float* __restrict__ C, int K, int M)
{
    __shared__ float As[32][68];
    __shared__ float Ws[32][68];
    gemm_body<RELU, RES>(A, W, bias, resid, C, K, M,
                         blockIdx.x * 64, blockIdx.y * 64, As, Ws);
}

// ---------------------------------------------------------------------------
// fused QKV GEMM + f16 pack. blockIdx.z: 0=Q (scaled, packed half2 row-major),
// 1=K (packed half2 row-major), 2=V (written as V^T half [H][N]).
// Qh/Kh: uint [N][64], slot s of row n = dims (2s, 2s+1). VhT[c*N + n].
// ---------------------------------------------------------------------------
__global__ __launch_bounds__(256) void qkv_gemm_pack_kernel(
    const float* __restrict__ A,
    const float* __restrict__ Wq, const float* __restrict__ Wk, const float* __restrict__ Wv,
    const float* __restrict__ bq, const float* __restrict__ bk, const float* __restrict__ bv,
    unsigned int* __restrict__ Qh, unsigned int* __restrict__ Kh,
    unsigned short* __restrict__ VhT)
{
    __shared__ float As[32][68];
    __shared__ float Ws[32][68];

    const float* W; const float* bias;
    if (blockIdx.z == 0)      { W = Wq; bias = bq; }
    else if (blockIdx.z == 1) { W = Wk; bias = bk; }
    else                      { W = Wv; bias = bv; }

    int tid = threadIdx.x;
    int colbase = blockIdx.x * 64;
    int rowbase = blockIdx.y * 64;
    int cx = tid % 16;
    int ry = tid / 16;
    int lr = tid % 64;
    int kq = tid / 64;
    int wk  = tid / 8;
    int wc0 = (tid % 8) * 8;

    float acc[4][4];
    #pragma unroll
    for (int i = 0; i < 4; ++i)
        #pragma unroll
        for (int j = 0; j < 4; ++j) acc[i][j] = 0.f;

    for (int kb = 0; kb < H; kb += 32) {
        #pragma unroll
        for (int h2 = 0; h2 < 2; ++h2) {
            int k0 = kq * 8 + h2 * 4;
            float4 a4 = *(const float4*)&A[(size_t)(rowbase + lr) * H + kb + k0];
            As[k0 + 0][lr] = a4.x;
            As[k0 + 1][lr] = a4.y;
            As[k0 + 2][lr] = a4.z;
            As[k0 + 3][lr] = a4.w;
        }
        *(float4*)&Ws[wk][wc0]     = *(const float4*)&W[(size_t)(kb + wk) * H + colbase + wc0];
        *(float4*)&Ws[wk][wc0 + 4] = *(const float4*)&W[(size_t)(kb + wk) * H + colbase + wc0 + 4];
        __syncthreads();

        #pragma unroll
        for (int kk = 0; kk < 32; ++kk) {
            float4 a = *(const float4*)&As[kk][ry * 4];
            float4 w = *(const float4*)&Ws[kk][cx * 4];
            float av[4] = {a.x, a.y, a.z, a.w};
            float wv[4] = {w.x, w.y, w.z, w.w};
            #pragma unroll
            for (int i = 0; i < 4; ++i)
                #pragma unroll
                for (int j = 0; j < 4; ++j)
                    acc[i][j] += av[i] * wv[j];
        }
        __syncthreads();
    }

    int c0 = colbase + cx * 4;
    float b0 = bias[c0], b1 = bias[c0 + 1], b2 = bias[c0 + 2], b3 = bias[c0 + 3];
    #pragma unroll
    for (int i = 0; i < 4; ++i) {
        int r  = rowbase + ry * 4 + i;
        float v0 = acc[i][0] + b0;
        float v1 = acc[i][1] + b1;
        float v2 = acc[i][2] + b2;
        float v3 = acc[i][3] + b3;
        if (blockIdx.z == 0) {
            v0 *= ATTN_SCALE; v1 *= ATTN_SCALE; v2 *= ATTN_SCALE; v3 *= ATTN_SCALE;
            uint2 pk = make_uint2(pack2(v0, v1), pack2(v2, v3));
            *(uint2*)&Qh[(size_t)r * 64 + (c0 >> 1)] = pk;
        } else if (blockIdx.z == 1) {
            uint2 pk = make_uint2(pack2(v0, v1), pack2(v2, v3));
            *(uint2*)&Kh[(size_t)r * 64 + (c0 >> 1)] = pk;
        } else {
            VhT[(size_t)(c0 + 0) * N_NODES + r] = __builtin_bit_cast(unsigned short, (_Float16)v0);
            VhT[(size_t)(c0 + 1) * N_NODES + r] = __builtin_bit_cast(unsigned short, (_Float16)v1);
            VhT[(size_t)(c0 + 2) * N_NODES + r] = __builtin_bit_cast(unsigned short, (_Float16)v2);
            VhT[(size_t)(c0 + 3) * N_NODES + r] = __builtin_bit_cast(unsigned short, (_Float16)v3);
        }
    }
}

// ---------------------------------------------------------------------------
// flash-attention partial, f16-dot2, dim-split lanes.
// grid (N/256, NHEADS, KCH), block 256 (4 waves) -> 4 blocks/CU, 4 waves/SIMD.
// Lane halves split head dims; each lane owns 2 queries; state ~80 regs.
// QK and PV use v_dot2_f32_f16; PV processes KEY PAIRS with p packed half2
// against a pair-major V LDS tile. Lazy-max online softmax with pair-max.
// partial layout (stride 36): {m, s, pad, pad, acc[32]}.
// ---------------------------------------------------------------------------
__global__ __launch_bounds__(256, 4) void attn_partial_kernel(
    const unsigned int* __restrict__ Qh, const unsigned int* __restrict__ Kh,
    const unsigned short* __restrict__ VhT, float* __restrict__ partial)
{
    __shared__ unsigned int Ks[64][20];  // [key][16 half2 dims], stride 80B (16-aligned)
    __shared__ unsigned int Vs[32][36];  // [kpair][32 dims], val = half2(V[2kp][d], V[2kp+1][d])

    int tid  = threadIdx.x;
    int t    = tid & 63;
    int w    = tid >> 6;        // wave 0..3
    int li   = t & 31;          // lane-in-half
    int lh   = t >> 5;          // dim half: dims lh*16 .. lh*16+15
    int head = blockIdx.y;
    int kc   = blockIdx.z;
    int qi0  = blockIdx.x * 256 + w * 64 + li;
    int qi1  = qi0 + 32;
    int kbase = kc * (N_NODES / KCH);   // 256 keys per chunk

    unsigned int q0[8], q1[8];
    {
        const uint4* a = (const uint4*)&Qh[(size_t)qi0 * 64 + head * 16 + lh * 8];
        const uint4* b = (const uint4*)&Qh[(size_t)qi1 * 64 + head * 16 + lh * 8];
        uint4 a0 = a[0], a1 = a[1], b0 = b[0], b1 = b[1];
        q0[0] = a0.x; q0[1] = a0.y; q0[2] = a0.z; q0[3] = a0.w;
        q0[4] = a1.x; q0[5] = a1.y; q0[6] = a1.z; q0[7] = a1.w;
        q1[0] = b0.x; q1[1] = b0.y; q1[2] = b0.z; q1[3] = b0.w;
        q1[4] = b1.x; q1[5] = b1.y; q1[6] = b1.z; q1[7] = b1.w;
    }

    float m0 = 0.f, s0 = 0.f, m1 = 0.f, s1 = 0.f;
    float acc0[16], acc1[16];
    #pragma unroll
    for (int j = 0; j < 16; ++j) { acc0[j] = 0.f; acc1[j] = 0.f; }

    int vkp = tid >> 3;          // V-fill: key pair 0..31
    int vseg = tid & 7;          // V-fill: dim segment (4 dims)

    for (int kt = 0; kt < N_NODES / KCH; kt += 64) {
        // K fill: thread (t=row, w=quarter): one uint4 (8 dims) per thread.
        {
            int krow = kbase + kt + t;
            *(uint4*)&Ks[t][w * 4] =
                *(const uint4*)&Kh[(size_t)krow * 64 + head * 16 + w * 4];
        }
        // V fill: pair-major. Vs[kp][d] = half2(V[2kp][d], V[2kp+1][d]) read
        // as one uint from V^T (consecutive k). 4 dims per thread.
        {
            int k0 = kbase + kt + 2 * vkp;
            const unsigned short* vb =
                VhT + (size_t)(head * 32 + vseg * 4) * N_NODES + k0;
            uint4 vv;
            vv.x = *(const unsigned int*)(vb);
            vv.y = *(const unsigned int*)(vb + N_NODES);
            vv.z = *(const unsigned int*)(vb + 2 * N_NODES);
            vv.w = *(const unsigned int*)(vb + 3 * N_NODES);
            *(uint4*)&Vs[vkp][vseg * 4] = vv;
        }
        __syncthreads();

        for (int kp = 0; kp < 32; ++kp) {
            unsigned int ka[8], kb[8];
            *(uint4*)&ka[0] = *(const uint4*)&Ks[2 * kp][lh * 8];
            *(uint4*)&ka[4] = *(const uint4*)&Ks[2 * kp][lh * 8 + 4];
            *(uint4*)&kb[0] = *(const uint4*)&Ks[2 * kp + 1][lh * 8];
            *(uint4*)&kb[4] = *(const uint4*)&Ks[2 * kp + 1][lh * 8 + 4];

            float dA0 = 0.f, dA1 = 0.f, dB0 = 0.f, dB1 = 0.f;
            #pragma unroll
            for (int j = 0; j < 8; ++j) {
                dA0 = fdot2(q0[j], ka[j], dA0);
                dA1 = fdot2(q1[j], ka[j], dA1);
                dB0 = fdot2(q0[j], kb[j], dB0);
                dB1 = fdot2(q1[j], kb[j], dB1);
            }
            // combine dim halves; a+b == b+a -> both halves bit-identical
            dA0 += __shfl_xor(dA0, 32);
            dA1 += __shfl_xor(dA1, 32);
            dB0 += __shfl_xor(dB0, 32);
            dB1 += __shfl_xor(dB1, 32);

            // lazy-max softmax, pair-max check (settle m BEFORE computing p)
            float mx0 = fmaxf(dA0, dB0);
            if (mx0 > m0 + DEFER_THR) {     // ~never taken: scores are small
                float c = __expf(m0 - mx0);
                s0 *= c;
                #pragma unroll
                for (int j = 0; j < 16; ++j) acc0[j] *= c;
                m0 = mx0;
            }
            float pA0 = __expf(dA0 - m0);
            float pB0 = __expf(dB0 - m0);
            s0 += pA0 + pB0;

            float mx1 = fmaxf(dA1, dB1);
            if (mx1 > m1 + DEFER_THR) {
                float c = __expf(m1 - mx1);
                s1 *= c;
                #pragma unroll
                for (int j = 0; j < 16; ++j) acc1[j] *= c;
                m1 = mx1;
            }
            float pA1 = __expf(dA1 - m1);
            float pB1 = __expf(dB1 - m1);
            s1 += pA1 + pB1;

            unsigned int pp0 = pack2(pA0, pB0);   // low = key 2kp, high = 2kp+1
            unsigned int pp1 = pack2(pA1, pB1);

            unsigned int vv[16];
            *(uint4*)&vv[0]  = *(const uint4*)&Vs[kp][lh * 16];
            *(uint4*)&vv[4]  = *(const uint4*)&Vs[kp][lh * 16 + 4];
            *(uint4*)&vv[8]  = *(const uint4*)&Vs[kp][lh * 16 + 8];
            *(uint4*)&vv[12] = *(const uint4*)&Vs[kp][lh * 16 + 12];
            #pragma unroll
            for (int j = 0; j < 16; ++j) {
                acc0[j] = fdot2(pp0, vv[j], acc0[j]);
                acc1[j] = fdot2(pp1, vv[j], acc1[j]);
            }
        }
        __syncthreads();
    }

    {
        float* pp = &partial[((size_t)(qi0 * NHEADS + head) * KCH + kc) * 36];
        if (lh == 0) { pp[0] = m0; pp[1] = s0; }
        #pragma unroll
        for (int j = 0; j < 16; j += 4)
            *(float4*)&pp[4 + lh * 16 + j] =
                make_float4(acc0[j], acc0[j + 1], acc0[j + 2], acc0[j + 3]);
    }
    {
        float* pp = &partial[((size_t)(qi1 * NHEADS + head) * KCH + kc) * 36];
        if (lh == 0) { pp[0] = m1; pp[1] = s1; }
        #pragma unroll
        for (int j = 0; j < 16; j += 4)
            *(float4*)&pp[4 + lh * 16 + j] =
                make_float4(acc1[j], acc1[j + 1], acc1[j + 2], acc1[j + 3]);
    }
}

// ---------------------------------------------------------------------------
// merge KCH partials per (n, head) -> o[n][head*32..]   (stride-36 partials)
// grid (N*NHEADS/256), block 256
// ---------------------------------------------------------------------------
__global__ __launch_bounds__(256) void attn_merge_kernel(
    const float* __restrict__ partial, float* __restrict__ o)
{
    int idx  = blockIdx.x * 256 + threadIdx.x;  // (n*NHEADS + head)
    int n    = idx / NHEADS;
    int head = idx % NHEADS;
    const float* pp = &partial[(size_t)idx * KCH * 36];

    float M = -1e30f;
    #pragma unroll
    for (int c = 0; c < KCH; ++c) M = fmaxf(M, pp[c * 36]);

    float S = 0.f;
    float out[32];
    #pragma unroll
    for (int j = 0; j < 32; ++j) out[j] = 0.f;

    #pragma unroll
    for (int c = 0; c < KCH; ++c) {
        float w = __expf(pp[c * 36] - M);
        S += pp[c * 36 + 1] * w;
        #pragma unroll
        for (int j = 0; j < 32; ++j) out[j] += w * pp[c * 36 + 4 + j];
    }
    float inv = 1.0f / S;
    #pragma unroll
    for (int j = 0; j < 32; ++j)
        o[(size_t)n * H + head * HDIM + j] = out[j] * inv;
}

// ---------------------------------------------------------------------------
// edge scorer: score[e] = relu(concat(h[src],h[dst]) @ We1 + be1) @ We2 + be2
// 64 edges/block, 256 threads, K=256 in 64-chunks, fused final dot.
// ROUND-12 FIX: thread column mapping changed from one contiguous 8-col run
// (cx*8..+7: Ws float4 reads at 8-float lane spacing -> bank (8cx)%32 hits
// only {0,8,16,24} -> 4-WAY CONFLICT, SQ_LDS_BANK_CONFLICT=2.3e7, 1.58x cost)
// to TWO float4 groups 64 apart ({cx*4..+3} and {64+cx*4..+3}: 4-float
// spacing -> 2-way aliasing, which is free per m136). Same column coverage.
// ---------------------------------------------------------------------------
__global__ __launch_bounds__(256) void edge_score_kernel(
    const float* __restrict__ h, const int* __restrict__ eidx,
    const float* __restrict__ We1, const float* __restrict__ be1,
    const float* __restrict__ We2, const float* __restrict__ be2,
    float* __restrict__ scores)
{
    __shared__ float As[64][68];    // [k][edge]
    __shared__ float Ws[64][132];   // [k][col]
    __shared__ float ssum[64];

    int tid   = threadIdx.x;
    int ebase = blockIdx.x * 64;
    int cx = tid % 16;            // cols cx*4..+3 and 64+cx*4..+3
    int ry = tid / 16;            // rows ry*4..+3

    int le   = tid % 64;
    int part = tid / 64;          // k-subrange part*16..+15
    int e    = ebase + le;
    int src  = eidx[2 * e];
    int dst  = eidx[2 * e + 1];

    float acc[4][8];
    #pragma unroll
    for (int i = 0; i < 4; ++i)
        #pragma unroll
        for (int j = 0; j < 8; ++j) acc[i][j] = 0.f;

    for (int kb = 0; kb < 2 * H; kb += 64) {
        #pragma unroll
        for (int qq = 0; qq < 4; ++qq) {
            int klocal = part * 16 + qq * 4;
            int k = kb + klocal;
            float4 val;
            if (k < H) val = *(const float4*)&h[(size_t)src * H + k];
            else       val = *(const float4*)&h[(size_t)dst * H + (k - H)];
            As[klocal + 0][le] = val.x;
            As[klocal + 1][le] = val.y;
            As[klocal + 2][le] = val.z;
            As[klocal + 3][le] = val.w;
        }
        {
            int kr = tid / 4, c0 = (tid % 4) * 32;
            #pragma unroll
            for (int qq = 0; qq < 8; ++qq) {
                *(float4*)&Ws[kr][c0 + qq * 4] =
                    *(const float4*)&We1[(size_t)(kb + kr) * H + c0 + qq * 4];
            }
        }
        __syncthreads();

        #pragma unroll
        for (int kk = 0; kk < 64; ++kk) {
            float4 a  = *(const float4*)&As[kk][ry * 4];
            float4 w0 = *(const float4*)&Ws[kk][cx * 4];         // cols cx*4..+3
            float4 w1 = *(const float4*)&Ws[kk][cx * 4 + 64];    // cols 64+cx*4..+3
            float av[4] = {a.x, a.y, a.z, a.w};
            float wv[8] = {w0.x, w0.y, w0.z, w0.w, w1.x, w1.y, w1.z, w1.w};
            #pragma unroll
            for (int i = 0; i < 4; ++i)
                #pragma unroll
                for (int j = 0; j < 8; ++j)
                    acc[i][j] += av[i] * wv[j];
        }
        __syncthreads();
    }

    if (tid < 64) ssum[tid] = 0.f;
    __syncthreads();

    float part_s[4] = {0.f, 0.f, 0.f, 0.f};
    #pragma unroll
    for (int j = 0; j < 8; ++j) {
        int col = (j < 4) ? (cx * 4 + j) : (64 + cx * 4 + (j - 4));
        float bb = be1[col];
        float w2 = We2[col];
        #pragma unroll
        for (int i = 0; i < 4; ++i) {
            float vv = acc[i][j] + bb;
            vv = fmaxf(vv, 0.f);
            part_s[i] += vv * w2;
        }
    }
    #pragma unroll
    for (int i = 0; i < 4; ++i)
        atomicAdd(&ssum[ry * 4 + i], part_s[i]);
    __syncthreads();

    if (tid < 64) scores[ebase + tid] = ssum[tid] + be2[0];
}

// ---------------------------------------------------------------------------
// global softmax over E scores: 3 passes (block online partials, merge, write)
// ---------------------------------------------------------------------------
__global__ __launch_bounds__(256) void softmax_p1(
    const float* __restrict__ sc, float* __restrict__ red)
{
    __shared__ float sm[256], ss[256];
    int tid = threadIdx.x;
    int base = blockIdx.x * 512;
    float x0 = sc[base + tid];
    float x1 = sc[base + 256 + tid];
    float m = fmaxf(x0, x1);
    float s = __expf(x0 - m) + __expf(x1 - m);
    sm[tid] = m; ss[tid] = s;
    __syncthreads();
    for (int off = 128; off > 0; off >>= 1) {
        if (tid < off) {
            float m2 = sm[tid + off], s2 = ss[tid + off];
            float mm = fmaxf(sm[tid], m2);
            ss[tid] = ss[tid] * __expf(sm[tid] - mm) + s2 * __expf(m2 - mm);
            sm[tid] = mm;
        }
        __syncthreads();
    }
    if (tid == 0) {
        red[blockIdx.x * 2]     = sm[0];
        red[blockIdx.x * 2 + 1] = ss[0];
    }
}

__global__ __launch_bounds__(256) void softmax_p2(
    const float* __restrict__ redin, float* __restrict__ redout)
{
    __shared__ float sm[256], ss[256];
    int tid = threadIdx.x;
    sm[tid] = redin[tid * 2];
    ss[tid] = redin[tid * 2 + 1];
    __syncthreads();
    for (int off = 128; off > 0; off >>= 1) {
        if (tid < off) {
            float m2 = sm[tid + off], s2 = ss[tid + off];
            float mm = fmaxf(sm[tid], m2);
            ss[tid] = ss[tid] * __expf(sm[tid] - mm) + s2 * __expf(m2 - mm);
            sm[tid] = mm;
        }
        __syncthreads();
    }
    if (tid == 0) { redout[0] = sm[0]; redout[1] = ss[0]; }
}

__global__ __launch_bounds__(256) void softmax_p3(
    const float* __restrict__ sc, const float* __restrict__ red,
    float* __restrict__ out)
{
    int i = blockIdx.x * 256 + threadIdx.x;
    float M = red[0], S = red[1];
    out[i] = __expf(sc[i] - M) / S;
}

// ---------------------------------------------------------------------------
// launcher
// ---------------------------------------------------------------------------
extern "C" void kernel_launch(void* const* d_in, const int* in_sizes, int n_in,
                              void* d_out, int out_size, void* d_ws, size_t ws_size,
                              hipStream_t stream)
{
    const float* x     = (const float*)d_in[0];
    const int*   eidx  = (const int*)  d_in[1];
    const float* W_in  = (const float*)d_in[2];
    const float* b_in  = (const float*)d_in[3];
    const float* Wq    = (const float*)d_in[4];
    const float* bq    = (const float*)d_in[5];
    const float* Wk    = (const float*)d_in[6];
    const float* bk    = (const float*)d_in[7];
    const float* Wv    = (const float*)d_in[8];
    const float* bv    = (const float*)d_in[9];
    const float* Wo    = (const float*)d_in[10];
    const float* bo    = (const float*)d_in[11];
    const float* ln1_g = (const float*)d_in[12];
    const float* ln1_b = (const float*)d_in[13];
    const float* ln2_g = (const float*)d_in[14];
    const float* ln2_b = (const float*)d_in[15];
    const float* Wf1   = (const float*)d_in[16];
    const float* bf1   = (const float*)d_in[17];
    const float* Wf2   = (const float*)d_in[18];
    const float* bf2   = (const float*)d_in[19];
    const float* We1   = (const float*)d_in[20];
    const float* be1   = (const float*)d_in[21];
    const float* We2   = (const float*)d_in[22];
    const float* be2   = (const float*)d_in[23];

    float* ws = (float*)d_ws;
    const size_t NH_ = (size_t)N_NODES * H;
    float* h  = ws;
    float* hn = h + NH_;
    unsigned int*   Qh  = (unsigned int*)(hn + NH_);          // N*64 uints
    unsigned int*   Kh  = Qh + (size_t)N_NODES * 64;          // N*64 uints
    unsigned short* VhT = (unsigned short*)(Kh + (size_t)N_NODES * 64);  // H*N halves
    float* o    = (float*)(VhT + (size_t)H * N_NODES);
    float* ff   = o + NH_;                                    // N * FF
    float* part = ff + (size_t)N_NODES * FFDIM;               // N*NHEADS*KCH*36
    float* esc  = part + (size_t)N_NODES * NHEADS * KCH * 36; // E
    float* red  = esc + EDGES;                                // 512 + 2

    float* out = (float*)d_out;

    in_proj_kernel<<<N_NODES, 128, 0, stream>>>(x, W_in, b_in, h);

    dim3 gh(H / 64, N_NODES / 64);
    dim3 gqkv(H / 64, N_NODES / 64, 3);
    for (int l = 0; l < LAYERS; ++l) {
        layernorm_kernel<<<N_NODES, 64, 0, stream>>>(h, ln1_g + l * H, ln1_b + l * H, hn);
        qkv_gemm_pack_kernel<<<gqkv, 256, 0, stream>>>(
            hn, Wq + (size_t)l * H * H, Wk + (size_t)l * H * H, Wv + (size_t)l * H * H,
            bq + l * H, bk + l * H, bv + l * H, Qh, Kh, VhT);
        attn_partial_kernel<<<dim3(N_NODES / 256, NHEADS, KCH), 256, 0, stream>>>(Qh, Kh, VhT, part);
        attn_merge_kernel<<<(N_NODES * NHEADS) / 256, 256, 0, stream>>>(part, o);
        gemm_kernel<false, true><<<gh, 256, 0, stream>>>(o, Wo + (size_t)l * H * H, bo + l * H, h, h, H, H);
        layernorm_kernel<<<N_NODES, 64, 0, stream>>>(h, ln2_g + l * H, ln2_b + l * H, hn);
        gemm_kernel<true, false><<<dim3(FFDIM / 64, N_NODES / 64), 256, 0, stream>>>(hn, Wf1 + (size_t)l * H * FFDIM, bf1 + l * FFDIM, nullptr, ff, H, FFDIM);
        gemm_kernel<false, true><<<gh, 256, 0, stream>>>(ff, Wf2 + (size_t)l * FFDIM * H, bf2 + l * H, h, h, FFDIM, H);
    }

    edge_score_kernel<<<EDGES / 64, 256, 0, stream>>>(h, eidx, We1, be1, We2, be2, esc);
    softmax_p1<<<256, 256, 0, stream>>>(esc, red);
    softmax_p2<<<1, 256, 0, stream>>>(red, red + 512);
    softmax_p3<<<EDGES / 256, 256, 0, stream>>>(esc, red + 512, out);
}

// Round 13
// 1019.132 us; speedup vs baseline: 1.0788x; 1.0788x over previous
//
#include <hip/hip_runtime.h>
#include <math.h>

#define N_NODES 4096
#define EDGES   131072
#define INDIM   10
#define H       128
#define LAYERS  4
#define NHEADS  4
#define HDIM    32
#define FFDIM   512
#define KCH     16         // key chunks for flash-attention partials
#define ATTN_SCALE 0.17677669529663687f  // 1/sqrt(32)
#define DEFER_THR 8.0f     // lazy-max threshold: rescale only when sv > m + THR

typedef _Float16 half2_t __attribute__((ext_vector_type(2)));

// v_dot2_f32_f16: d = a.x*b.x + a.y*b.y + c  (2 MACs/instr, fp32 accumulate)
__device__ __forceinline__ float fdot2(unsigned int a, unsigned int b, float c) {
#if __has_builtin(__builtin_amdgcn_fdot2)
    return __builtin_amdgcn_fdot2(__builtin_bit_cast(half2_t, a),
                                  __builtin_bit_cast(half2_t, b), c, false);
#else
    float r;
    asm("v_dot2_f32_f16 %0, %1, %2, %3" : "=v"(r) : "v"(a), "v"(b), "v"(c));
    return r;
#endif
}

// v_cvt_pkrtz_f16_f32: pack two floats to half2 (round-toward-zero).
// NOTE: the builtin returns __fp16 ext_vector_type(2), which clang treats as
// a DIFFERENT type from _Float16 vectors — use auto + bit_cast (round-10 fix).
__device__ __forceinline__ unsigned int pack2(float a, float b) {
    auto h = __builtin_amdgcn_cvt_pkrtz(a, b);   // a -> low, b -> high
    return __builtin_bit_cast(unsigned int, h);
}

// ---------------------------------------------------------------------------
// input projection: h[n][j] = b_in[j] + sum_k x[n][k] * W_in[k][j]   (K=10)
// ---------------------------------------------------------------------------
__global__ __launch_bounds__(128) void in_proj_kernel(
    const float* __restrict__ x, const float* __restrict__ W_in,
    const float* __restrict__ b_in, float* __restrict__ h)
{
    int n = blockIdx.x;
    int j = threadIdx.x;
    float acc = b_in[j];
    #pragma unroll
    for (int k = 0; k < INDIM; ++k)
        acc += x[n * INDIM + k] * W_in[k * H + j];
    h[n * H + j] = acc;
}

// ---------------------------------------------------------------------------
// layernorm over last dim (128). one wave per row, 2 elements per lane.
// ---------------------------------------------------------------------------
__global__ __launch_bounds__(64) void layernorm_kernel(
    const float* __restrict__ h, const float* __restrict__ g,
    const float* __restrict__ b, float* __restrict__ out)
{
    int n = blockIdx.x;
    int t = threadIdx.x;
    float a0 = h[n * H + t];
    float a1 = h[n * H + t + 64];
    float sum = a0 + a1;
    float sq  = a0 * a0 + a1 * a1;
    #pragma unroll
    for (int off = 1; off < 64; off <<= 1) {
        sum += __shfl_xor(sum, off, 64);
        sq  += __shfl_xor(sq,  off, 64);
    }
    float mu  = sum * (1.0f / H);
    float var = sq * (1.0f / H) - mu * mu;
    float r   = rsqrtf(var + 1e-5f);
    out[n * H + t]      = (a0 - mu) * r * g[t]      + b[t];
    out[n * H + t + 64] = (a1 - mu) * r * g[t + 64] + b[t + 64];
}

// ---------------------------------------------------------------------------
// shared tiled-GEMM body: C[r][c] = (RES ? resid : 0) + act(bias[c] + A@W)
// A [rows,K] rm, W [K,M] rm.  BM=64, BN=64, BK=32, 256 thr, 4x4 micro.
// ---------------------------------------------------------------------------
template<bool RELU, bool RES>
__device__ __forceinline__ void gemm_body(
    const float* __restrict__ A, const float* __restrict__ W,
    const float* __restrict__ bias, const float* __restrict__ resid,
    float* __restrict__ C, int K, int M, int colbase, int rowbase,
    float (*As)[68], float (*Ws)[68])
{
    int tid = threadIdx.x;
    int cx = tid % 16;           // col group: cols cx*4..+3
    int ry = tid / 16;           // row group: rows ry*4..+3

    int lr = tid % 64;           // A-load row
    int kq = tid / 64;           // A-load k-subblock (0..3)
    int wk  = tid / 8;           // W-load k row (0..31)
    int wc0 = (tid % 8) * 8;     // W-load col start

    float acc[4][4];
    #pragma unroll
    for (int i = 0; i < 4; ++i)
        #pragma unroll
        for (int j = 0; j < 4; ++j) acc[i][j] = 0.f;

    for (int kb = 0; kb < K; kb += 32) {
        #pragma unroll
        for (int h2 = 0; h2 < 2; ++h2) {
            int k0 = kq * 8 + h2 * 4;
            float4 a4 = *(const float4*)&A[(size_t)(rowbase + lr) * K + kb + k0];
            As[k0 + 0][lr] = a4.x;
            As[k0 + 1][lr] = a4.y;
            As[k0 + 2][lr] = a4.z;
            As[k0 + 3][lr] = a4.w;
        }
        *(float4*)&Ws[wk][wc0]     = *(const float4*)&W[(size_t)(kb + wk) * M + colbase + wc0];
        *(float4*)&Ws[wk][wc0 + 4] = *(const float4*)&W[(size_t)(kb + wk) * M + colbase + wc0 + 4];
        __syncthreads();

        #pragma unroll
        for (int kk = 0; kk < 32; ++kk) {
            float4 a = *(const float4*)&As[kk][ry * 4];
            float4 w = *(const float4*)&Ws[kk][cx * 4];
            float av[4] = {a.x, a.y, a.z, a.w};
            float wv[4] = {w.x, w.y, w.z, w.w};
            #pragma unroll
            for (int i = 0; i < 4; ++i)
                #pragma unroll
                for (int j = 0; j < 4; ++j)
                    acc[i][j] += av[i] * wv[j];
        }
        __syncthreads();
    }

    #pragma unroll
    for (int i = 0; i < 4; ++i) {
        int r  = rowbase + ry * 4 + i;
        int c0 = colbase + cx * 4;
        float v0 = acc[i][0] + bias[c0 + 0];
        float v1 = acc[i][1] + bias[c0 + 1];
        float v2 = acc[i][2] + bias[c0 + 2];
        float v3 = acc[i][3] + bias[c0 + 3];
        if (RELU) {
            v0 = fmaxf(v0, 0.f); v1 = fmaxf(v1, 0.f);
            v2 = fmaxf(v2, 0.f); v3 = fmaxf(v3, 0.f);
        }
        if (RES) {
            const float4 rr = *(const float4*)&resid[(size_t)r * M + c0];
            v0 += rr.x; v1 += rr.y; v2 += rr.z; v3 += rr.w;
        }
        float4 outv = make_float4(v0, v1, v2, v3);
        *(float4*)&C[(size_t)r * M + c0] = outv;
    }
}

template<bool RELU, bool RES>
__global__ __launch_bounds__(256) void gemm_kernel(
    const float* __restrict__ A, const float* __restrict__ W,
    const float* __restrict__ bias, const float* __restrict__ resid,
    float* __restrict__ C, int K, int M)
{
    __shared__ float As[32][68];
    __shared__ float Ws[32][68];
    gemm_body<RELU, RES>(A, W, bias, resid, C, K, M,
                         blockIdx.x * 64, blockIdx.y * 64, As, Ws);
}

// ---------------------------------------------------------------------------
// fused QKV GEMM + f16 pack. blockIdx.z: 0=Q (scaled, packed half2 row-major),
// 1=K (packed half2 row-major), 2=V (written as V^T half [H][N]).
// Qh/Kh: uint [N][64], slot s of row n = dims (2s, 2s+1). VhT[c*N + n].
// ---------------------------------------------------------------------------
__global__ __launch_bounds__(256) void qkv_gemm_pack_kernel(
    const float* __restrict__ A,
    const float* __restrict__ Wq, const float* __restrict__ Wk, const float* __restrict__ Wv,
    const float* __restrict__ bq, const float* __restrict__ bk, const float* __restrict__ bv,
    unsigned int* __restrict__ Qh, unsigned int* __restrict__ Kh,
    unsigned short* __restrict__ VhT)
{
    __shared__ float As[32][68];
    __shared__ float Ws[32][68];

    const float* W; const float* bias;
    if (blockIdx.z == 0)      { W = Wq; bias = bq; }
    else if (blockIdx.z == 1) { W = Wk; bias = bk; }
    else                      { W = Wv; bias = bv; }

    int tid = threadIdx.x;
    int colbase = blockIdx.x * 64;
    int rowbase = blockIdx.y * 64;
    int cx = tid % 16;
    int ry = tid / 16;
    int lr = tid % 64;
    int kq = tid / 64;
    int wk  = tid / 8;
    int wc0 = (tid % 8) * 8;

    float acc[4][4];
    #pragma unroll
    for (int i = 0; i < 4; ++i)
        #pragma unroll
        for (int j = 0; j < 4; ++j) acc[i][j] = 0.f;

    for (int kb = 0; kb < H; kb += 32) {
        #pragma unroll
        for (int h2 = 0; h2 < 2; ++h2) {
            int k0 = kq * 8 + h2 * 4;
            float4 a4 = *(const float4*)&A[(size_t)(rowbase + lr) * H + kb + k0];
            As[k0 + 0][lr] = a4.x;
            As[k0 + 1][lr] = a4.y;
            As[k0 + 2][lr] = a4.z;
            As[k0 + 3][lr] = a4.w;
        }
        *(float4*)&Ws[wk][wc0]     = *(const float4*)&W[(size_t)(kb + wk) * H + colbase + wc0];
        *(float4*)&Ws[wk][wc0 + 4] = *(const float4*)&W[(size_t)(kb + wk) * H + colbase + wc0 + 4];
        __syncthreads();

        #pragma unroll
        for (int kk = 0; kk < 32; ++kk) {
            float4 a = *(const float4*)&As[kk][ry * 4];
            float4 w = *(const float4*)&Ws[kk][cx * 4];
            float av[4] = {a.x, a.y, a.z, a.w};
            float wv[4] = {w.x, w.y, w.z, w.w};
            #pragma unroll
            for (int i = 0; i < 4; ++i)
                #pragma unroll
                for (int j = 0; j < 4; ++j)
                    acc[i][j] += av[i] * wv[j];
        }
        __syncthreads();
    }

    int c0 = colbase + cx * 4;
    float b0 = bias[c0], b1 = bias[c0 + 1], b2 = bias[c0 + 2], b3 = bias[c0 + 3];
    #pragma unroll
    for (int i = 0; i < 4; ++i) {
        int r  = rowbase + ry * 4 + i;
        float v0 = acc[i][0] + b0;
        float v1 = acc[i][1] + b1;
        float v2 = acc[i][2] + b2;
        float v3 = acc[i][3] + b3;
        if (blockIdx.z == 0) {
            v0 *= ATTN_SCALE; v1 *= ATTN_SCALE; v2 *= ATTN_SCALE; v3 *= ATTN_SCALE;
            uint2 pk = make_uint2(pack2(v0, v1), pack2(v2, v3));
            *(uint2*)&Qh[(size_t)r * 64 + (c0 >> 1)] = pk;
        } else if (blockIdx.z == 1) {
            uint2 pk = make_uint2(pack2(v0, v1), pack2(v2, v3));
            *(uint2*)&Kh[(size_t)r * 64 + (c0 >> 1)] = pk;
        } else {
            VhT[(size_t)(c0 + 0) * N_NODES + r] = __builtin_bit_cast(unsigned short, (_Float16)v0);
            VhT[(size_t)(c0 + 1) * N_NODES + r] = __builtin_bit_cast(unsigned short, (_Float16)v1);
            VhT[(size_t)(c0 + 2) * N_NODES + r] = __builtin_bit_cast(unsigned short, (_Float16)v2);
            VhT[(size_t)(c0 + 3) * N_NODES + r] = __builtin_bit_cast(unsigned short, (_Float16)v3);
        }
    }
}

// ---------------------------------------------------------------------------
// flash-attention partial, f16-dot2, dim-split lanes.
// grid (N/256, NHEADS, KCH), block 256 (4 waves) -> 4 blocks/CU, 4 waves/SIMD.
// Lane halves split head dims; each lane owns 2 queries; state ~80 regs.
// QK and PV use v_dot2_f32_f16; PV processes KEY PAIRS with p packed half2
// against a pair-major V LDS tile. Lazy-max online softmax with pair-max.
// partial layout (stride 36): {m, s, pad, pad, acc[32]}.
// ---------------------------------------------------------------------------
__global__ __launch_bounds__(256, 4) void attn_partial_kernel(
    const unsigned int* __restrict__ Qh, const unsigned int* __restrict__ Kh,
    const unsigned short* __restrict__ VhT, float* __restrict__ partial)
{
    __shared__ unsigned int Ks[64][20];  // [key][16 half2 dims], stride 80B (16-aligned)
    __shared__ unsigned int Vs[32][36];  // [kpair][32 dims], val = half2(V[2kp][d], V[2kp+1][d])

    int tid  = threadIdx.x;
    int t    = tid & 63;
    int w    = tid >> 6;        // wave 0..3
    int li   = t & 31;          // lane-in-half
    int lh   = t >> 5;          // dim half: dims lh*16 .. lh*16+15
    int head = blockIdx.y;
    int kc   = blockIdx.z;
    int qi0  = blockIdx.x * 256 + w * 64 + li;
    int qi1  = qi0 + 32;
    int kbase = kc * (N_NODES / KCH);   // 256 keys per chunk

    unsigned int q0[8], q1[8];
    {
        const uint4* a = (const uint4*)&Qh[(size_t)qi0 * 64 + head * 16 + lh * 8];
        const uint4* b = (const uint4*)&Qh[(size_t)qi1 * 64 + head * 16 + lh * 8];
        uint4 a0 = a[0], a1 = a[1], b0 = b[0], b1 = b[1];
        q0[0] = a0.x; q0[1] = a0.y; q0[2] = a0.z; q0[3] = a0.w;
        q0[4] = a1.x; q0[5] = a1.y; q0[6] = a1.z; q0[7] = a1.w;
        q1[0] = b0.x; q1[1] = b0.y; q1[2] = b0.z; q1[3] = b0.w;
        q1[4] = b1.x; q1[5] = b1.y; q1[6] = b1.z; q1[7] = b1.w;
    }

    float m0 = 0.f, s0 = 0.f, m1 = 0.f, s1 = 0.f;
    float acc0[16], acc1[16];
    #pragma unroll
    for (int j = 0; j < 16; ++j) { acc0[j] = 0.f; acc1[j] = 0.f; }

    int vkp = tid >> 3;          // V-fill: key pair 0..31
    int vseg = tid & 7;          // V-fill: dim segment (4 dims)

    for (int kt = 0; kt < N_NODES / KCH; kt += 64) {
        // K fill: thread (t=row, w=quarter): one uint4 (8 dims) per thread.
        {
            int krow = kbase + kt + t;
            *(uint4*)&Ks[t][w * 4] =
                *(const uint4*)&Kh[(size_t)krow * 64 + head * 16 + w * 4];
        }
        // V fill: pair-major. Vs[kp][d] = half2(V[2kp][d], V[2kp+1][d]) read
        // as one uint from V^T (consecutive k). 4 dims per thread.
        {
            int k0 = kbase + kt + 2 * vkp;
            const unsigned short* vb =
                VhT + (size_t)(head * 32 + vseg * 4) * N_NODES + k0;
            uint4 vv;
            vv.x = *(const unsigned int*)(vb);
            vv.y = *(const unsigned int*)(vb + N_NODES);
            vv.z = *(const unsigned int*)(vb + 2 * N_NODES);
            vv.w = *(const unsigned int*)(vb + 3 * N_NODES);
            *(uint4*)&Vs[vkp][vseg * 4] = vv;
        }
        __syncthreads();

        for (int kp = 0; kp < 32; ++kp) {
            unsigned int ka[8], kb[8];
            *(uint4*)&ka[0] = *(const uint4*)&Ks[2 * kp][lh * 8];
            *(uint4*)&ka[4] = *(const uint4*)&Ks[2 * kp][lh * 8 + 4];
            *(uint4*)&kb[0] = *(const uint4*)&Ks[2 * kp + 1][lh * 8];
            *(uint4*)&kb[4] = *(const uint4*)&Ks[2 * kp + 1][lh * 8 + 4];

            float dA0 = 0.f, dA1 = 0.f, dB0 = 0.f, dB1 = 0.f;
            #pragma unroll
            for (int j = 0; j < 8; ++j) {
                dA0 = fdot2(q0[j], ka[j], dA0);
                dA1 = fdot2(q1[j], ka[j], dA1);
                dB0 = fdot2(q0[j], kb[j], dB0);
                dB1 = fdot2(q1[j], kb[j], dB1);
            }
            // combine dim halves; a+b == b+a -> both halves bit-identical
            dA0 += __shfl_xor(dA0, 32);
            dA1 += __shfl_xor(dA1, 32);
            dB0 += __shfl_xor(dB0, 32);
            dB1 += __shfl_xor(dB1, 32);

            // lazy-max softmax, pair-max check (settle m BEFORE computing p)
            float mx0 = fmaxf(dA0, dB0);
            if (mx0 > m0 + DEFER_THR) {     // ~never taken: scores are small
                float c = __expf(m0 - mx0);
                s0 *= c;
                #pragma unroll
                for (int j = 0; j < 16; ++j) acc0[j] *= c;
                m0 = mx0;
            }
            float pA0 = __expf(dA0 - m0);
            float pB0 = __expf(dB0 - m0);
            s0 += pA0 + pB0;

            float mx1 = fmaxf(dA1, dB1);
            if (mx1 > m1 + DEFER_THR) {
                float c = __expf(m1 - mx1);
                s1 *= c;
                #pragma unroll
                for (int j = 0; j < 16; ++j) acc1[j] *= c;
                m1 = mx1;
            }
            float pA1 = __expf(dA1 - m1);
            float pB1 = __expf(dB1 - m1);
            s1 += pA1 + pB1;

            unsigned int pp0 = pack2(pA0, pB0);   // low = key 2kp, high = 2kp+1
            unsigned int pp1 = pack2(pA1, pB1);

            unsigned int vv[16];
            *(uint4*)&vv[0]  = *(const uint4*)&Vs[kp][lh * 16];
            *(uint4*)&vv[4]  = *(const uint4*)&Vs[kp][lh * 16 + 4];
            *(uint4*)&vv[8]  = *(const uint4*)&Vs[kp][lh * 16 + 8];
            *(uint4*)&vv[12] = *(const uint4*)&Vs[kp][lh * 16 + 12];
            #pragma unroll
            for (int j = 0; j < 16; ++j) {
                acc0[j] = fdot2(pp0, vv[j], acc0[j]);
                acc1[j] = fdot2(pp1, vv[j], acc1[j]);
            }
        }
        __syncthreads();
    }

    {
        float* pp = &partial[((size_t)(qi0 * NHEADS + head) * KCH + kc) * 36];
        if (lh == 0) { pp[0] = m0; pp[1] = s0; }
        #pragma unroll
        for (int j = 0; j < 16; j += 4)
            *(float4*)&pp[4 + lh * 16 + j] =
                make_float4(acc0[j], acc0[j + 1], acc0[j + 2], acc0[j + 3]);
    }
    {
        float* pp = &partial[((size_t)(qi1 * NHEADS + head) * KCH + kc) * 36];
        if (lh == 0) { pp[0] = m1; pp[1] = s1; }
        #pragma unroll
        for (int j = 0; j < 16; j += 4)
            *(float4*)&pp[4 + lh * 16 + j] =
                make_float4(acc1[j], acc1[j + 1], acc1[j + 2], acc1[j + 3]);
    }
}

// ---------------------------------------------------------------------------
// merge KCH partials per (n, head) -> o[n][head*32..]   (stride-36 partials)
// grid (N*NHEADS/256), block 256
// ---------------------------------------------------------------------------
__global__ __launch_bounds__(256) void attn_merge_kernel(
    const float* __restrict__ partial, float* __restrict__ o)
{
    int idx  = blockIdx.x * 256 + threadIdx.x;  // (n*NHEADS + head)
    int n    = idx / NHEADS;
    int head = idx % NHEADS;
    const float* pp = &partial[(size_t)idx * KCH * 36];

    float M = -1e30f;
    #pragma unroll
    for (int c = 0; c < KCH; ++c) M = fmaxf(M, pp[c * 36]);

    float S = 0.f;
    float out[32];
    #pragma unroll
    for (int j = 0; j < 32; ++j) out[j] = 0.f;

    #pragma unroll
    for (int c = 0; c < KCH; ++c) {
        float w = __expf(pp[c * 36] - M);
        S += pp[c * 36 + 1] * w;
        #pragma unroll
        for (int j = 0; j < 32; ++j) out[j] += w * pp[c * 36 + 4 + j];
    }
    float inv = 1.0f / S;
    #pragma unroll
    for (int j = 0; j < 32; ++j)
        o[(size_t)n * H + head * HDIM + j] = out[j] * inv;
}

// ---------------------------------------------------------------------------
// pack h[N][H] fp32 -> Hh[N][64] uint (half2 of dims 2s,2s+1)
// ---------------------------------------------------------------------------
__global__ __launch_bounds__(256) void pack_h_kernel(
    const float* __restrict__ h, unsigned int* __restrict__ Hh)
{
    int i = blockIdx.x * 256 + threadIdx.x;     // i < N*64
    float2 v = *(const float2*)&h[(size_t)i * 2];
    Hh[i] = pack2(v.x, v.y);
}

// pack We1[2H][H] fp32 -> Weh[128][128] uint: Weh[kp][c]=half2(We1[2kp][c],We1[2kp+1][c])
__global__ __launch_bounds__(256) void pack_we1_kernel(
    const float* __restrict__ We1, unsigned int* __restrict__ Weh)
{
    int i  = blockIdx.x * 256 + threadIdx.x;    // i < 128*128
    int kp = i >> 7;
    int c  = i & 127;
    Weh[i] = pack2(We1[(size_t)(2 * kp) * H + c], We1[(size_t)(2 * kp + 1) * H + c]);
}

// ---------------------------------------------------------------------------
// edge scorer (f16-dot2): score[e] = relu(concat(h[src],h[dst])@We1+be1)@We2+be2
// 64 edges/block, 256 threads. ROUND-13: round 12 showed the fp32 version is
// LDS-READ-THROUGHPUT bound (conflicts fixed 2.3e7->6.3e6 with NO time change;
// 3 b128 reads feeding 32 FMAs = ~123us of serialized LDS-unit time/CU).
// f16 half2 packing halves BOTH the k-iterations (128 kpairs vs 256 k) and
// the MACs-per-instr (fdot2): per kpair 3 b128 reads feed 32 fdot2 = 64 MACs.
// LDS: Ah[32][68]+Wh[32][132] uints ~= 26 KB -> more blocks/CU.
// A-operand comes pre-packed from Hh (gathered per edge), W from Weh.
// ---------------------------------------------------------------------------
__global__ __launch_bounds__(256) void edge_score_kernel(
    const unsigned int* __restrict__ Hh, const int* __restrict__ eidx,
    const unsigned int* __restrict__ Weh, const float* __restrict__ be1,
    const float* __restrict__ We2, const float* __restrict__ be2,
    float* __restrict__ scores)
{
    __shared__ unsigned int Ah[32][68];    // [kpair][edge]
    __shared__ unsigned int Wh[32][132];   // [kpair][col]
    __shared__ float ssum[64];

    int tid   = threadIdx.x;
    int ebase = blockIdx.x * 64;
    int cx = tid % 16;            // cols cx*4..+3 and 64+cx*4..+3
    int ry = tid / 16;            // edges ry*4..+3

    int le = tid & 63;            // A-fill edge
    int w4 = tid >> 6;            // A-fill kpair-quarter (0..3): kpairs w4*8..+7
    int e   = ebase + le;
    int src = eidx[2 * e];
    int dst = eidx[2 * e + 1];

    int wkr = tid / 8;            // W-fill kpair row (0..31)
    int wc0 = (tid % 8) * 16;     // W-fill col start (16 uints = 4x uint4)

    float acc[4][8];
    #pragma unroll
    for (int i = 0; i < 4; ++i)
        #pragma unroll
        for (int j = 0; j < 8; ++j) acc[i][j] = 0.f;

    #pragma unroll
    for (int c2 = 0; c2 < 4; ++c2) {        // 4 chunks of 32 kpairs (K=256)
        // A fill: chunk 0,1 from src (uint idx c2*32+kp), 2,3 from dst (-64)
        {
            int node  = (c2 < 2) ? src : dst;
            int ubase = (c2 & 1) * 32 + w4 * 8;
            uint4 u0 = *(const uint4*)&Hh[(size_t)node * 64 + ubase];
            uint4 u1 = *(const uint4*)&Hh[(size_t)node * 64 + ubase + 4];
            Ah[w4 * 8 + 0][le] = u0.x; Ah[w4 * 8 + 1][le] = u0.y;
            Ah[w4 * 8 + 2][le] = u0.z; Ah[w4 * 8 + 3][le] = u0.w;
            Ah[w4 * 8 + 4][le] = u1.x; Ah[w4 * 8 + 5][le] = u1.y;
            Ah[w4 * 8 + 6][le] = u1.z; Ah[w4 * 8 + 7][le] = u1.w;
        }
        // W fill: 32x128 uints, 16 per thread
        {
            #pragma unroll
            for (int j = 0; j < 4; ++j) {
                *(uint4*)&Wh[wkr][wc0 + j * 4] =
                    *(const uint4*)&Weh[(size_t)(c2 * 32 + wkr) * 128 + wc0 + j * 4];
            }
        }
        __syncthreads();

        #pragma unroll
        for (int kp = 0; kp < 32; ++kp) {
            uint4 a4 = *(const uint4*)&Ah[kp][ry * 4];
            uint4 w0 = *(const uint4*)&Wh[kp][cx * 4];         // cols cx*4..+3
            uint4 w1 = *(const uint4*)&Wh[kp][cx * 4 + 64];    // cols 64+cx*4..+3
            unsigned int av[4] = {a4.x, a4.y, a4.z, a4.w};
            unsigned int wv[8] = {w0.x, w0.y, w0.z, w0.w, w1.x, w1.y, w1.z, w1.w};
            #pragma unroll
            for (int i = 0; i < 4; ++i)
                #pragma unroll
                for (int j = 0; j < 8; ++j)
                    acc[i][j] = fdot2(av[i], wv[j], acc[i][j]);
        }
        __syncthreads();
    }

    if (tid < 64) ssum[tid] = 0.f;
    __syncthreads();

    float part_s[4] = {0.f, 0.f, 0.f, 0.f};
    #pragma unroll
    for (int j = 0; j < 8; ++j) {
        int col = (j < 4) ? (cx * 4 + j) : (64 + cx * 4 + (j - 4));
        float bb = be1[col];
        float w2 = We2[col];
        #pragma unroll
        for (int i = 0; i < 4; ++i) {
            float vv = acc[i][j] + bb;
            vv = fmaxf(vv, 0.f);
            part_s[i] += vv * w2;
        }
    }
    #pragma unroll
    for (int i = 0; i < 4; ++i)
        atomicAdd(&ssum[ry * 4 + i], part_s[i]);
    __syncthreads();

    if (tid < 64) scores[ebase + tid] = ssum[tid] + be2[0];
}

// ---------------------------------------------------------------------------
// global softmax over E scores: 3 passes (block online partials, merge, write)
// ---------------------------------------------------------------------------
__global__ __launch_bounds__(256) void softmax_p1(
    const float* __restrict__ sc, float* __restrict__ red)
{
    __shared__ float sm[256], ss[256];
    int tid = threadIdx.x;
    int base = blockIdx.x * 512;
    float x0 = sc[base + tid];
    float x1 = sc[base + 256 + tid];
    float m = fmaxf(x0, x1);
    float s = __expf(x0 - m) + __expf(x1 - m);
    sm[tid] = m; ss[tid] = s;
    __syncthreads();
    for (int off = 128; off > 0; off >>= 1) {
        if (tid < off) {
            float m2 = sm[tid + off], s2 = ss[tid + off];
            float mm = fmaxf(sm[tid], m2);
            ss[tid] = ss[tid] * __expf(sm[tid] - mm) + s2 * __expf(m2 - mm);
            sm[tid] = mm;
        }
        __syncthreads();
    }
    if (tid == 0) {
        red[blockIdx.x * 2]     = sm[0];
        red[blockIdx.x * 2 + 1] = ss[0];
    }
}

__global__ __launch_bounds__(256) void softmax_p2(
    const float* __restrict__ redin, float* __restrict__ redout)
{
    __shared__ float sm[256], ss[256];
    int tid = threadIdx.x;
    sm[tid] = redin[tid * 2];
    ss[tid] = redin[tid * 2 + 1];
    __syncthreads();
    for (int off = 128; off > 0; off >>= 1) {
        if (tid < off) {
            float m2 = sm[tid + off], s2 = ss[tid + off];
            float mm = fmaxf(sm[tid], m2);
            ss[tid] = ss[tid] * __expf(sm[tid] - mm) + s2 * __expf(m2 - mm);
            sm[tid] = mm;
        }
        __syncthreads();
    }
    if (tid == 0) { redout[0] = sm[0]; redout[1] = ss[0]; }
}

__global__ __launch_bounds__(256) void softmax_p3(
    const float* __restrict__ sc, const float* __restrict__ red,
    float* __restrict__ out)
{
    int i = blockIdx.x * 256 + threadIdx.x;
    float M = red[0], S = red[1];
    out[i] = __expf(sc[i] - M) / S;
}

// ---------------------------------------------------------------------------
// launcher
// ---------------------------------------------------------------------------
extern "C" void kernel_launch(void* const* d_in, const int* in_sizes, int n_in,
                              void* d_out, int out_size, void* d_ws, size_t ws_size,
                              hipStream_t stream)
{
    const float* x     = (const float*)d_in[0];
    const int*   eidx  = (const int*)  d_in[1];
    const float* W_in  = (const float*)d_in[2];
    const float* b_in  = (const float*)d_in[3];
    const float* Wq    = (const float*)d_in[4];
    const float* bq    = (const float*)d_in[5];
    const float* Wk    = (const float*)d_in[6];
    const float* bk    = (const float*)d_in[7];
    const float* Wv    = (const float*)d_in[8];
    const float* bv    = (const float*)d_in[9];
    const float* Wo    = (const float*)d_in[10];
    const float* bo    = (const float*)d_in[11];
    const float* ln1_g = (const float*)d_in[12];
    const float* ln1_b = (const float*)d_in[13];
    const float* ln2_g = (const float*)d_in[14];
    const float* ln2_b = (const float*)d_in[15];
    const float* Wf1   = (const float*)d_in[16];
    const float* bf1   = (const float*)d_in[17];
    const float* Wf2   = (const float*)d_in[18];
    const float* bf2   = (const float*)d_in[19];
    const float* We1   = (const float*)d_in[20];
    const float* be1   = (const float*)d_in[21];
    const float* We2   = (const float*)d_in[22];
    const float* be2   = (const float*)d_in[23];

    float* ws = (float*)d_ws;
    const size_t NH_ = (size_t)N_NODES * H;
    float* h  = ws;
    float* hn = h + NH_;
    unsigned int*   Qh  = (unsigned int*)(hn + NH_);          // N*64 uints
    unsigned int*   Kh  = Qh + (size_t)N_NODES * 64;          // N*64 uints
    unsigned short* VhT = (unsigned short*)(Kh + (size_t)N_NODES * 64);  // H*N halves
    float* o    = (float*)(VhT + (size_t)H * N_NODES);
    float* ff   = o + NH_;                                    // N * FF
    float* part = ff + (size_t)N_NODES * FFDIM;               // N*NHEADS*KCH*36
    float* esc  = part + (size_t)N_NODES * NHEADS * KCH * 36; // E
    float* red  = esc + EDGES;                                // 512 + 2
    unsigned int* Hh  = (unsigned int*)(red + 520);           // N*64 uints
    unsigned int* Weh = Hh + (size_t)N_NODES * 64;            // 128*128 uints

    float* out = (float*)d_out;

    in_proj_kernel<<<N_NODES, 128, 0, stream>>>(x, W_in, b_in, h);

    dim3 gh(H / 64, N_NODES / 64);
    dim3 gqkv(H / 64, N_NODES / 64, 3);
    for (int l = 0; l < LAYERS; ++l) {
        layernorm_kernel<<<N_NODES, 64, 0, stream>>>(h, ln1_g + l * H, ln1_b + l * H, hn);
        qkv_gemm_pack_kernel<<<gqkv, 256, 0, stream>>>(
            hn, Wq + (size_t)l * H * H, Wk + (size_t)l * H * H, Wv + (size_t)l * H * H,
            bq + l * H, bk + l * H, bv + l * H, Qh, Kh, VhT);
        attn_partial_kernel<<<dim3(N_NODES / 256, NHEADS, KCH), 256, 0, stream>>>(Qh, Kh, VhT, part);
        attn_merge_kernel<<<(N_NODES * NHEADS) / 256, 256, 0, stream>>>(part, o);
        gemm_kernel<false, true><<<gh, 256, 0, stream>>>(o, Wo + (size_t)l * H * H, bo + l * H, h, h, H, H);
        layernorm_kernel<<<N_NODES, 64, 0, stream>>>(h, ln2_g + l * H, ln2_b + l * H, hn);
        gemm_kernel<true, false><<<dim3(FFDIM / 64, N_NODES / 64), 256, 0, stream>>>(hn, Wf1 + (size_t)l * H * FFDIM, bf1 + l * FFDIM, nullptr, ff, H, FFDIM);
        gemm_kernel<false, true><<<gh, 256, 0, stream>>>(ff, Wf2 + (size_t)l * FFDIM * H, bf2 + l * H, h, h, FFDIM, H);
    }

    pack_h_kernel<<<(N_NODES * 64) / 256, 256, 0, stream>>>(h, Hh);
    pack_we1_kernel<<<(128 * 128) / 256, 256, 0, stream>>>(We1, Weh);
    edge_score_kernel<<<EDGES / 64, 256, 0, stream>>>(Hh, eidx, Weh, be1, We2, be2, esc);
    softmax_p1<<<256, 256, 0, stream>>>(esc, red);
    softmax_p2<<<1, 256, 0, stream>>>(red, red + 512);
    softmax_p3<<<EDGES / 256, 256, 0, stream>>>(esc, red + 512, out);
}